// Round 11
// baseline (84.756 us; speedup 1.0000x reference)
//
#include <hip/hip_runtime.h>
#include <hip/hip_bf16.h>
#include <cstddef>

// Pipeline (5 kernels):
//  kWprep  : W1,W2 -> split-bf16 WT [term][z][n][k] in d_out ctx region (2MB)
//  kMgemmB : split-bf16 3-term MFMA GEMM, 32x128 tile; epilogue stores
//            exp2 of prescaled activation (factored sigmoid)
//  kLogSoft: transpose-layout (lane<->s) logits, ZERO shuffles, fused
//            softmax -> final weights in attnw
//  kEncT   : enc -> bf16 transpose encT[b][e][s] in ws (X1e dead)
//  kCtxMM  : MFMA batched context GEMM; converts attnw f32->bf16 in staging

constexpr int nBt = 16, nSq = 128, nTq = 128, nEd = 512;

typedef __attribute__((ext_vector_type(4))) float f32x4;
typedef __attribute__((ext_vector_type(8))) short s16x8;

#define PRESCALE 2.8853900817779268f  /* 2*log2(e) */
#define LOG2E 1.4426950408889634f

__device__ __forceinline__ unsigned short to_bf(float f) {
    unsigned u = __builtin_bit_cast(unsigned, f);
    return (unsigned short)((u + 0x7FFFu + ((u >> 16) & 1u)) >> 16);  // RNE
}
__device__ __forceinline__ float from_bf(unsigned short h) {
    unsigned u = ((unsigned)h) << 16;
    return __builtin_bit_cast(float, u);
}

// ---- kWprep: WT[term][z][n][k] = split_bf16(W_z[k][n]) (r8-proven) ------
__global__ __launch_bounds__(256) void kWprep(
    const float* __restrict__ W1, const float* __restrict__ W2,
    unsigned short* __restrict__ WT)
{
    const int z = blockIdx.z;
    const float* W = z ? W2 : W1;
    __shared__ float tl[32][33];
    const int r  = threadIdx.x >> 3;
    const int c4 = (threadIdx.x & 7) * 4;
    const int kB = blockIdx.y * 32;
    const int nB = blockIdx.x * 32;
    const float4 v = *(const float4*)&W[(size_t)(kB + r) * nEd + nB + c4];
    tl[r][c4 + 0] = v.x; tl[r][c4 + 1] = v.y;
    tl[r][c4 + 2] = v.z; tl[r][c4 + 3] = v.w;
    __syncthreads();
    unsigned short hh[4], ll[4];
    #pragma unroll
    for (int i = 0; i < 4; ++i) {
        const float x = tl[c4 + i][r];
        hh[i] = to_bf(x);
        ll[i] = to_bf(x - from_bf(hh[i]));
    }
    const size_t o = ((size_t)z * nEd + nB + r) * nEd + kB + c4;
    *(ushort4*)&WT[o] = *(ushort4*)hh;
    *(ushort4*)&WT[(size_t)2 * nEd * nEd + o] = *(ushort4*)ll;
}

// ---- kMgemmB: C_z = exp2((A_z @ W_z [+bias]) * PRESCALE) ----------------
// Tile 32(M) x 128(N), BK=64; 4 waves side-by-side in N (wave tile 32x32).
__global__ __launch_bounds__(256) void kMgemmB(
    const float* __restrict__ A0, const float* __restrict__ A1,
    const unsigned short* __restrict__ WT, const float* __restrict__ bias,
    float* __restrict__ C0, float* __restrict__ C1)
{
    const int z = blockIdx.z;
    const float* __restrict__ A = z ? A1 : A0;
    const unsigned short* __restrict__ Wh = WT + (size_t)z * nEd * nEd;
    const unsigned short* __restrict__ Wl = Wh + (size_t)2 * nEd * nEd;
    float* __restrict__ C = z ? C1 : C0;

    __shared__ unsigned short sAh[32][72];
    __shared__ unsigned short sAl[32][72];
    __shared__ unsigned short sBh[128][72];
    __shared__ unsigned short sBl[128][72];

    const int tid  = threadIdx.x;
    const int lane = tid & 63;
    const int wv   = tid >> 6;
    const int rowB = blockIdx.y * 32;
    const int colB = blockIdx.x * 128;

    const int ar = tid >> 3, ak = (tid & 7) * 8;    // A: 8 f32/thread
    const int br = tid >> 1, bc = (tid & 1) * 32;   // B: 32 ushort/thread/plane

    f32x4 acc[2][2] = {};
    const int l15 = lane & 15;
    const int kh  = lane >> 4;

    for (int k0 = 0; k0 < nEd; k0 += 64) {
        const float4 ga0 = *(const float4*)&A[(size_t)(rowB + ar) * nEd + k0 + ak];
        const float4 ga1 = *(const float4*)&A[(size_t)(rowB + ar) * nEd + k0 + ak + 4];
        const size_t wo = (size_t)(colB + br) * nEd + k0 + bc;
        s16x8 gh[4], gl[4];
        #pragma unroll
        for (int j = 0; j < 4; ++j) {
            gh[j] = *(const s16x8*)&Wh[wo + 8 * j];
            gl[j] = *(const s16x8*)&Wl[wo + 8 * j];
        }

        __syncthreads();
        {
            const float a8[8] = {ga0.x, ga0.y, ga0.z, ga0.w,
                                 ga1.x, ga1.y, ga1.z, ga1.w};
            unsigned short h[8], l[8];
            #pragma unroll
            for (int i = 0; i < 8; ++i) {
                h[i] = to_bf(a8[i]);
                l[i] = to_bf(a8[i] - from_bf(h[i]));
            }
            *(ushort4*)&sAh[ar][ak]     = *(ushort4*)&h[0];
            *(ushort4*)&sAh[ar][ak + 4] = *(ushort4*)&h[4];
            *(ushort4*)&sAl[ar][ak]     = *(ushort4*)&l[0];
            *(ushort4*)&sAl[ar][ak + 4] = *(ushort4*)&l[4];
        }
        #pragma unroll
        for (int j = 0; j < 4; ++j) {
            *(s16x8*)&sBh[br][bc + 8 * j] = gh[j];
            *(s16x8*)&sBl[br][bc + 8 * j] = gl[j];
        }
        __syncthreads();

        #pragma unroll
        for (int kk = 0; kk < 2; ++kk) {
            s16x8 fAh[2], fAl[2], fBh[2], fBl[2];
            #pragma unroll
            for (int mi = 0; mi < 2; ++mi) {
                fAh[mi] = *(const s16x8*)&sAh[mi * 16 + l15][kk * 32 + kh * 8];
                fAl[mi] = *(const s16x8*)&sAl[mi * 16 + l15][kk * 32 + kh * 8];
            }
            #pragma unroll
            for (int ni = 0; ni < 2; ++ni) {
                fBh[ni] = *(const s16x8*)&sBh[wv * 32 + ni * 16 + l15][kk * 32 + kh * 8];
                fBl[ni] = *(const s16x8*)&sBl[wv * 32 + ni * 16 + l15][kk * 32 + kh * 8];
            }
            #pragma unroll
            for (int mi = 0; mi < 2; ++mi)
                #pragma unroll
                for (int ni = 0; ni < 2; ++ni) {
                    f32x4 a = acc[mi][ni];
                    a = __builtin_amdgcn_mfma_f32_16x16x32_bf16(fAh[mi], fBh[ni], a, 0, 0, 0);
                    a = __builtin_amdgcn_mfma_f32_16x16x32_bf16(fAl[mi], fBh[ni], a, 0, 0, 0);
                    a = __builtin_amdgcn_mfma_f32_16x16x32_bf16(fAh[mi], fBl[ni], a, 0, 0, 0);
                    acc[mi][ni] = a;
                }
        }
    }

    // epilogue: exp2 of prescaled activation (factored-sigmoid prep)
    #pragma unroll
    for (int ni = 0; ni < 2; ++ni) {
        const int col = colB + wv * 32 + ni * 16 + l15;
        const float bval = z ? bias[col] : 0.0f;
        #pragma unroll
        for (int mi = 0; mi < 2; ++mi) {
            #pragma unroll
            for (int r = 0; r < 4; ++r) {
                const int row = rowB + mi * 16 + kh * 4 + r;
                C[(size_t)row * nEd + col] =
                    __builtin_amdgcn_exp2f((acc[mi][ni][r] + bval) * PRESCALE);
            }
        }
    }
}

// ---- kLogSoft: transpose-layout logits (lane<->s) + fused softmax -------
// Grid (T/4=32, B=16), 4 waves. Wave w: s-half = w&1 (sr = 64*(w&1)+lane),
// t-pair = (w>>1)*2. Per-lane accumulation over e -> zero shuffles.
// Constant sum(V) term dropped (softmax shift-invariant).
__global__ __launch_bounds__(256) void kLogSoft(
    const float* __restrict__ X1e,  // [B*S,E] exp2'd
    const float* __restrict__ X2e,  // [B*T,E] exp2'd (bias folded)
    const float* __restrict__ V,    // [E]
    float* __restrict__ attnw)      // [B*T,S] out: softmax weights
{
    const int tg = blockIdx.x, b = blockIdx.y;
    const int tid  = threadIdx.x;
    const int lane = tid & 63;
    const int w    = tid >> 6;
    const int t0 = tg * 4;

    __shared__ float x1t[128][68];  // [s][e_local], stride 68: f4-aligned, 2/bank
    __shared__ float x2t[4][64];
    __shared__ float nvt[64];
    __shared__ float sm[4][nSq];

    const int sr = 64 * (w & 1) + lane;
    const int tp = (w >> 1) * 2;
    const int srow = tid >> 1;
    const int scol = (tid & 1) * 32;

    const float* X1b = X1e + (size_t)b * nSq * nEd;
    float acc0 = 0.f, acc1 = 0.f;

    float4 pf[8];
    #pragma unroll
    for (int j = 0; j < 8; ++j)
        pf[j] = *(const float4*)&X1b[(size_t)srow * nEd + scol + 4 * j];

    for (int c = 0; c < 8; ++c) {
        const int e0 = c * 64;
        __syncthreads();   // prior chunk's readers done
        #pragma unroll
        for (int j = 0; j < 8; ++j)
            *(float4*)&x1t[srow][scol + 4 * j] = pf[j];
        if (tid < 64) {
            const int tt = tid >> 4, ee = (tid & 15) * 4;
            *(float4*)&x2t[tt][ee] =
                *(const float4*)&X2e[((size_t)b * nTq + t0 + tt) * nEd + e0 + ee];
        } else if (tid < 80) {
            const int ee = (tid - 64) * 4;
            const float4 v = *(const float4*)&V[e0 + ee];
            nvt[ee + 0] = -2.f * v.x; nvt[ee + 1] = -2.f * v.y;
            nvt[ee + 2] = -2.f * v.z; nvt[ee + 3] = -2.f * v.w;
        }
        __syncthreads();

        if (c < 7) {   // prefetch next chunk under compute
            #pragma unroll
            for (int j = 0; j < 8; ++j)
                pf[j] = *(const float4*)&X1b[(size_t)srow * nEd + e0 + 64 + scol + 4 * j];
        }

        #pragma unroll 4
        for (int e4 = 0; e4 < 64; e4 += 4) {
            const float4 x1v = *(const float4*)&x1t[sr][e4];
            const float4 xa  = *(const float4*)&x2t[tp][e4];
            const float4 xb  = *(const float4*)&x2t[tp + 1][e4];
            const float4 nv  = *(const float4*)&nvt[e4];
            acc0 += nv.x * __builtin_amdgcn_rcpf(x1v.x * xa.x + 1.0f);
            acc1 += nv.x * __builtin_amdgcn_rcpf(x1v.x * xb.x + 1.0f);
            acc0 += nv.y * __builtin_amdgcn_rcpf(x1v.y * xa.y + 1.0f);
            acc1 += nv.y * __builtin_amdgcn_rcpf(x1v.y * xb.y + 1.0f);
            acc0 += nv.z * __builtin_amdgcn_rcpf(x1v.z * xa.z + 1.0f);
            acc1 += nv.z * __builtin_amdgcn_rcpf(x1v.z * xb.z + 1.0f);
            acc0 += nv.w * __builtin_amdgcn_rcpf(x1v.w * xa.w + 1.0f);
            acc1 += nv.w * __builtin_amdgcn_rcpf(x1v.w * xb.w + 1.0f);
        }
    }

    sm[tp + 0][sr] = acc0;
    sm[tp + 1][sr] = acc1;
    __syncthreads();

    // softmax: wave w owns local t = w
    {
        const float l0 = sm[w][lane], l1 = sm[w][lane + 64];
        float m = fmaxf(l0, l1);
        #pragma unroll
        for (int off = 32; off >= 1; off >>= 1)
            m = fmaxf(m, __shfl_xor(m, off));
        const float e0 = __builtin_amdgcn_exp2f((l0 - m) * LOG2E);
        const float e1 = __builtin_amdgcn_exp2f((l1 - m) * LOG2E);
        float sum = e0 + e1;
        #pragma unroll
        for (int off = 32; off >= 1; off >>= 1)
            sum += __shfl_xor(sum, off);
        const float inv = __builtin_amdgcn_rcpf(sum);
        float* ap = attnw + ((size_t)b * nTq + t0 + w) * nSq;
        ap[lane]      = e0 * inv;
        ap[lane + 64] = e1 * inv;
    }
}

// ---- kEncT: encT[b][e][s] = bf16(enc[b][s][e]) (r9-proven) --------------
__global__ __launch_bounds__(256) void kEncT(
    const float* __restrict__ enc, unsigned short* __restrict__ encT)
{
    const int b = blockIdx.z;
    __shared__ float tl[32][33];
    const int r  = threadIdx.x >> 3;
    const int c4 = (threadIdx.x & 7) * 4;
    const int sB = blockIdx.y * 32;
    const int eB = blockIdx.x * 32;
    const float4 v = *(const float4*)&enc[((size_t)b * nSq + sB + r) * nEd + eB + c4];
    tl[r][c4 + 0] = v.x; tl[r][c4 + 1] = v.y;
    tl[r][c4 + 2] = v.z; tl[r][c4 + 3] = v.w;
    __syncthreads();
    unsigned short o[4];
    #pragma unroll
    for (int i = 0; i < 4; ++i) o[i] = to_bf(tl[c4 + i][r]);
    *(ushort4*)&encT[((size_t)b * nEd + eB + r) * nSq + sB + c4] = *(ushort4*)o;
}

// ---- kCtxMM: ctx[b] = bf16(attnw[b]) @ encT[b]^T (batched MFMA) ---------
__global__ __launch_bounds__(256) void kCtxMM(
    const float* __restrict__ attnw,          // [B*T,S] f32 weights
    const unsigned short* __restrict__ encT,  // [B*E,S]
    float* __restrict__ ctx)                  // [B*T,E]
{
    const int b  = blockIdx.z;
    const int tB = blockIdx.y * 32;
    const int eB = blockIdx.x * 64;

    __shared__ unsigned short sA[32][136];
    __shared__ unsigned short sB[64][136];

    const int tid  = threadIdx.x;
    const int lane = tid & 63;
    const int w    = tid >> 6;
    const int wm = (w >> 1) * 16;
    const int wn = (w & 1) * 32;
    const int l15 = lane & 15;
    const int kh  = lane >> 4;

    {   // stage A: convert 32x128 f32 weights -> bf16 (16/thread)
        const int r = tid >> 3, c = (tid & 7) * 16;
        const float* ap = &attnw[((size_t)b * nTq + tB + r) * nSq + c];
        unsigned short h[16];
        #pragma unroll
        for (int q = 0; q < 4; ++q) {
            const float4 v = *(const float4*)(ap + 4 * q);
            h[4 * q + 0] = to_bf(v.x); h[4 * q + 1] = to_bf(v.y);
            h[4 * q + 2] = to_bf(v.z); h[4 * q + 3] = to_bf(v.w);
        }
        *(s16x8*)&sA[r][c]     = *(s16x8*)&h[0];
        *(s16x8*)&sA[r][c + 8] = *(s16x8*)&h[8];
    }
    {   // stage B: 64x128 ushorts (32/thread)
        const int r = tid >> 2, c = (tid & 3) * 32;
        const size_t o = ((size_t)b * nEd + eB + r) * nSq + c;
        *(s16x8*)&sB[r][c]      = *(const s16x8*)&encT[o];
        *(s16x8*)&sB[r][c + 8]  = *(const s16x8*)&encT[o + 8];
        *(s16x8*)&sB[r][c + 16] = *(const s16x8*)&encT[o + 16];
        *(s16x8*)&sB[r][c + 24] = *(const s16x8*)&encT[o + 24];
    }
    __syncthreads();

    f32x4 acc[2] = {};
    #pragma unroll
    for (int kk = 0; kk < 4; ++kk) {
        const s16x8 fA = *(const s16x8*)&sA[wm + l15][kk * 32 + kh * 8];
        #pragma unroll
        for (int ni = 0; ni < 2; ++ni) {
            const s16x8 fB = *(const s16x8*)&sB[wn + ni * 16 + l15][kk * 32 + kh * 8];
            acc[ni] = __builtin_amdgcn_mfma_f32_16x16x32_bf16(fA, fB, acc[ni], 0, 0, 0);
        }
    }

    #pragma unroll
    for (int ni = 0; ni < 2; ++ni) {
        const int e = eB + wn + ni * 16 + l15;
        #pragma unroll
        for (int r = 0; r < 4; ++r) {
            const int t = tB + wm + kh * 4 + r;
            ctx[((size_t)b * nTq + t) * nEd + e] = acc[ni][r];
        }
    }
}

extern "C" void kernel_launch(void* const* d_in, const int* in_sizes, int n_in,
                              void* d_out, int out_size, void* d_ws, size_t ws_size,
                              hipStream_t stream) {
    const float* enc = (const float*)d_in[0];   // [16,128,512]
    const float* dec = (const float*)d_in[1];   // [16,128,512]
    const float* W1  = (const float*)d_in[2];   // [512,512]
    const float* W2  = (const float*)d_in[3];   // [512,512]
    const float* bv  = (const float*)d_in[4];   // [512]
    const float* V   = (const float*)d_in[5];   // [512]

    float* ctx   = (float*)d_out;                           // [16,128,512] 4MB
    float* attnw = (float*)d_out + (size_t)nBt * nTq * nEd; // [16,128,128] 1MB

    // WT (2MB) in ctx region — dead before kCtxMM writes ctx.
    unsigned short* WT = (unsigned short*)d_out;

    float* ws0 = (float*)d_ws;                    // exp2((enc@W1)*PS), 4MB
    float* ws1 = ws0 + (size_t)nBt * nSq * nEd;   // exp2((dec@W2+b)*PS), 4MB
    // After kLogSoft, X1e region is reused:
    unsigned short* encT = (unsigned short*)d_ws;           // 2MB

    kWprep<<<dim3(nEd / 32, nEd / 32, 2), dim3(256), 0, stream>>>(W1, W2, WT);
    kMgemmB<<<dim3(nEd / 128, (nBt * nSq) / 32, 2), dim3(256), 0, stream>>>(
        enc, dec, WT, bv, ws0, ws1);
    kLogSoft<<<dim3(nTq / 4, nBt), dim3(256), 0, stream>>>(ws0, ws1, V, attnw);
    kEncT<<<dim3(nEd / 32, nSq / 32, nBt), dim3(256), 0, stream>>>(enc, encT);
    kCtxMM<<<dim3(nEd / 64, nTq / 32, nBt), dim3(256), 0, stream>>>(
        attnw, encT, ctx);
}

// Round 12
// 60.987 us; speedup vs baseline: 1.3897x; 1.3897x over previous
//
#include <hip/hip_runtime.h>
#include <hip/hip_bf16.h>
#include <cstddef>

// Pipeline (6 kernels) — r10 structure with r11's faster GEMM:
//  kWprep  : W1,W2 -> split-bf16 WT [term][z][n][k] in d_out ctx region (2MB)
//  kMgemmB : split-bf16 3-term MFMA GEMM, 32x128 tile (r11-proven, ~2x r10);
//            epilogue stores exp2 of prescaled activation (factored sigmoid)
//  kLogits : register-based factored-sigmoid scores, 8-t sharing per wave,
//            zero LDS staging (r11 lesson: LDS tile = bank conflicts + occupancy)
//  kEncT   : enc -> bf16 transpose encT[b][e][s] in ws (X1e dead)
//  kSoft   : softmax per (b,t): f32 weights -> attnw, bf16 weights -> scratch
//  kCtxMM  : MFMA batched context GEMM (r9/r10-proven)

constexpr int nBt = 16, nSq = 128, nTq = 128, nEd = 512;

typedef __attribute__((ext_vector_type(4))) float f32x4;
typedef __attribute__((ext_vector_type(8))) short s16x8;

#define PRESCALE 2.8853900817779268f  /* 2*log2(e) */
#define LOG2E 1.4426950408889634f

__device__ __forceinline__ unsigned short to_bf(float f) {
    unsigned u = __builtin_bit_cast(unsigned, f);
    return (unsigned short)((u + 0x7FFFu + ((u >> 16) & 1u)) >> 16);  // RNE
}
__device__ __forceinline__ float from_bf(unsigned short h) {
    unsigned u = ((unsigned)h) << 16;
    return __builtin_bit_cast(float, u);
}

// ---- kWprep: WT[term][z][n][k] = split_bf16(W_z[k][n]) (r8-proven) ------
__global__ __launch_bounds__(256) void kWprep(
    const float* __restrict__ W1, const float* __restrict__ W2,
    unsigned short* __restrict__ WT)
{
    const int z = blockIdx.z;
    const float* W = z ? W2 : W1;
    __shared__ float tl[32][33];
    const int r  = threadIdx.x >> 3;
    const int c4 = (threadIdx.x & 7) * 4;
    const int kB = blockIdx.y * 32;
    const int nB = blockIdx.x * 32;
    const float4 v = *(const float4*)&W[(size_t)(kB + r) * nEd + nB + c4];
    tl[r][c4 + 0] = v.x; tl[r][c4 + 1] = v.y;
    tl[r][c4 + 2] = v.z; tl[r][c4 + 3] = v.w;
    __syncthreads();
    unsigned short hh[4], ll[4];
    #pragma unroll
    for (int i = 0; i < 4; ++i) {
        const float x = tl[c4 + i][r];
        hh[i] = to_bf(x);
        ll[i] = to_bf(x - from_bf(hh[i]));
    }
    const size_t o = ((size_t)z * nEd + nB + r) * nEd + kB + c4;
    *(ushort4*)&WT[o] = *(ushort4*)hh;
    *(ushort4*)&WT[(size_t)2 * nEd * nEd + o] = *(ushort4*)ll;
}

// ---- kMgemmB: C_z = exp2((A_z @ W_z [+bias]) * PRESCALE) (r11-proven) ---
// Tile 32(M) x 128(N), BK=64; 4 waves side-by-side in N (wave tile 32x32).
__global__ __launch_bounds__(256) void kMgemmB(
    const float* __restrict__ A0, const float* __restrict__ A1,
    const unsigned short* __restrict__ WT, const float* __restrict__ bias,
    float* __restrict__ C0, float* __restrict__ C1)
{
    const int z = blockIdx.z;
    const float* __restrict__ A = z ? A1 : A0;
    const unsigned short* __restrict__ Wh = WT + (size_t)z * nEd * nEd;
    const unsigned short* __restrict__ Wl = Wh + (size_t)2 * nEd * nEd;
    float* __restrict__ C = z ? C1 : C0;

    __shared__ unsigned short sAh[32][72];
    __shared__ unsigned short sAl[32][72];
    __shared__ unsigned short sBh[128][72];
    __shared__ unsigned short sBl[128][72];

    const int tid  = threadIdx.x;
    const int lane = tid & 63;
    const int wv   = tid >> 6;
    const int rowB = blockIdx.y * 32;
    const int colB = blockIdx.x * 128;

    const int ar = tid >> 3, ak = (tid & 7) * 8;    // A: 8 f32/thread
    const int br = tid >> 1, bc = (tid & 1) * 32;   // B: 32 ushort/thread/plane

    f32x4 acc[2][2] = {};
    const int l15 = lane & 15;
    const int kh  = lane >> 4;

    for (int k0 = 0; k0 < nEd; k0 += 64) {
        const float4 ga0 = *(const float4*)&A[(size_t)(rowB + ar) * nEd + k0 + ak];
        const float4 ga1 = *(const float4*)&A[(size_t)(rowB + ar) * nEd + k0 + ak + 4];
        const size_t wo = (size_t)(colB + br) * nEd + k0 + bc;
        s16x8 gh[4], gl[4];
        #pragma unroll
        for (int j = 0; j < 4; ++j) {
            gh[j] = *(const s16x8*)&Wh[wo + 8 * j];
            gl[j] = *(const s16x8*)&Wl[wo + 8 * j];
        }

        __syncthreads();
        {
            const float a8[8] = {ga0.x, ga0.y, ga0.z, ga0.w,
                                 ga1.x, ga1.y, ga1.z, ga1.w};
            unsigned short h[8], l[8];
            #pragma unroll
            for (int i = 0; i < 8; ++i) {
                h[i] = to_bf(a8[i]);
                l[i] = to_bf(a8[i] - from_bf(h[i]));
            }
            *(ushort4*)&sAh[ar][ak]     = *(ushort4*)&h[0];
            *(ushort4*)&sAh[ar][ak + 4] = *(ushort4*)&h[4];
            *(ushort4*)&sAl[ar][ak]     = *(ushort4*)&l[0];
            *(ushort4*)&sAl[ar][ak + 4] = *(ushort4*)&l[4];
        }
        #pragma unroll
        for (int j = 0; j < 4; ++j) {
            *(s16x8*)&sBh[br][bc + 8 * j] = gh[j];
            *(s16x8*)&sBl[br][bc + 8 * j] = gl[j];
        }
        __syncthreads();

        #pragma unroll
        for (int kk = 0; kk < 2; ++kk) {
            s16x8 fAh[2], fAl[2], fBh[2], fBl[2];
            #pragma unroll
            for (int mi = 0; mi < 2; ++mi) {
                fAh[mi] = *(const s16x8*)&sAh[mi * 16 + l15][kk * 32 + kh * 8];
                fAl[mi] = *(const s16x8*)&sAl[mi * 16 + l15][kk * 32 + kh * 8];
            }
            #pragma unroll
            for (int ni = 0; ni < 2; ++ni) {
                fBh[ni] = *(const s16x8*)&sBh[wv * 32 + ni * 16 + l15][kk * 32 + kh * 8];
                fBl[ni] = *(const s16x8*)&sBl[wv * 32 + ni * 16 + l15][kk * 32 + kh * 8];
            }
            #pragma unroll
            for (int mi = 0; mi < 2; ++mi)
                #pragma unroll
                for (int ni = 0; ni < 2; ++ni) {
                    f32x4 a = acc[mi][ni];
                    a = __builtin_amdgcn_mfma_f32_16x16x32_bf16(fAh[mi], fBh[ni], a, 0, 0, 0);
                    a = __builtin_amdgcn_mfma_f32_16x16x32_bf16(fAl[mi], fBh[ni], a, 0, 0, 0);
                    a = __builtin_amdgcn_mfma_f32_16x16x32_bf16(fAh[mi], fBl[ni], a, 0, 0, 0);
                    acc[mi][ni] = a;
                }
        }
    }

    #pragma unroll
    for (int ni = 0; ni < 2; ++ni) {
        const int col = colB + wv * 32 + ni * 16 + l15;
        const float bval = z ? bias[col] : 0.0f;
        #pragma unroll
        for (int mi = 0; mi < 2; ++mi) {
            #pragma unroll
            for (int r = 0; r < 4; ++r) {
                const int row = rowB + mi * 16 + kh * 4 + r;
                C[(size_t)row * nEd + col] =
                    __builtin_amdgcn_exp2f((acc[mi][ni][r] + bval) * PRESCALE);
            }
        }
    }
}

// ---- kLogits: register-based factored-sigmoid scores, 8-t sharing ------
// Grid (4 sg, 16 tg, 16 b), 4 waves. Wave w: s in [sg*32+w*8, +8),
// t in [tg*8, +8). All t-broadcast values in registers; no LDS, no barriers.
// Per element: 1 fma(denom) + 1 rcp + 1 fma(acc). vsum dropped
// (softmax shift-invariant).
__global__ __launch_bounds__(256) void kLogits(
    const float* __restrict__ X1e,  // [B*S,E] exp2'd
    const float* __restrict__ X2e,  // [B*T,E] exp2'd (bias folded)
    const float* __restrict__ V,    // [E]
    float* __restrict__ lg)         // [B*T,S]
{
    const int sg = blockIdx.x, tg = blockIdx.y, b = blockIdx.z;
    const int tid  = threadIdx.x;
    const int lane = tid & 63;
    const int w    = tid >> 6;
    const int s0 = sg * 32 + w * 8;
    const int t0 = tg * 8;

    const float4* vp = (const float4*)V;
    const float4  v0 = vp[lane * 2], v1 = vp[lane * 2 + 1];
    const float4 n0 = make_float4(-2.f * v0.x, -2.f * v0.y, -2.f * v0.z, -2.f * v0.w);
    const float4 n1 = make_float4(-2.f * v1.x, -2.f * v1.y, -2.f * v1.z, -2.f * v1.w);

    float4 c0[8], c1[8];   // exp2(c) per local t
    #pragma unroll
    for (int i = 0; i < 8; ++i) {
        const float4* xp = (const float4*)(X2e + ((size_t)b * nTq + t0 + i) * nEd);
        c0[i] = xp[lane * 2];
        c1[i] = xp[lane * 2 + 1];
    }

    for (int si = 0; si < 8; ++si) {
        const int s = s0 + si;
        const float4* ap = (const float4*)(X1e + ((size_t)b * nSq + s) * nEd);
        const float4 x0 = ap[lane * 2], x1 = ap[lane * 2 + 1];
        float acc[8];
        #pragma unroll
        for (int t = 0; t < 8; ++t) {
            float a;
            a  = n0.x * __builtin_amdgcn_rcpf(fmaf(x0.x, c0[t].x, 1.0f));
            a += n0.y * __builtin_amdgcn_rcpf(fmaf(x0.y, c0[t].y, 1.0f));
            a += n0.z * __builtin_amdgcn_rcpf(fmaf(x0.z, c0[t].z, 1.0f));
            a += n0.w * __builtin_amdgcn_rcpf(fmaf(x0.w, c0[t].w, 1.0f));
            a += n1.x * __builtin_amdgcn_rcpf(fmaf(x1.x, c1[t].x, 1.0f));
            a += n1.y * __builtin_amdgcn_rcpf(fmaf(x1.y, c1[t].y, 1.0f));
            a += n1.z * __builtin_amdgcn_rcpf(fmaf(x1.z, c1[t].z, 1.0f));
            a += n1.w * __builtin_amdgcn_rcpf(fmaf(x1.w, c1[t].w, 1.0f));
            acc[t] = a;
        }
        #pragma unroll
        for (int t = 0; t < 8; ++t) {
            float a = acc[t];
            #pragma unroll
            for (int off = 32; off >= 1; off >>= 1)
                a += __shfl_xor(a, off);
            if (lane == 0)
                lg[((size_t)b * nTq + t0 + t) * nSq + s] = a;
        }
    }
}

// ---- kEncT: encT[b][e][s] = bf16(enc[b][s][e]) (r9-proven) --------------
__global__ __launch_bounds__(256) void kEncT(
    const float* __restrict__ enc, unsigned short* __restrict__ encT)
{
    const int b = blockIdx.z;
    __shared__ float tl[32][33];
    const int r  = threadIdx.x >> 3;
    const int c4 = (threadIdx.x & 7) * 4;
    const int sB = blockIdx.y * 32;
    const int eB = blockIdx.x * 32;
    const float4 v = *(const float4*)&enc[((size_t)b * nSq + sB + r) * nEd + eB + c4];
    tl[r][c4 + 0] = v.x; tl[r][c4 + 1] = v.y;
    tl[r][c4 + 2] = v.z; tl[r][c4 + 3] = v.w;
    __syncthreads();
    unsigned short o[4];
    #pragma unroll
    for (int i = 0; i < 4; ++i) o[i] = to_bf(tl[c4 + i][r]);
    *(ushort4*)&encT[((size_t)b * nEd + eB + r) * nSq + sB + c4] = *(ushort4*)o;
}

// ---- kSoft: softmax per (b,t); f32 weights + bf16 weights (r9-proven) ---
__global__ __launch_bounds__(256) void kSoft(
    float* __restrict__ attnw,            // in: logits, out: weights
    unsigned short* __restrict__ attnbf)  // [B*T,S] bf16 weights
{
    const int bt = blockIdx.x * 4 + (threadIdx.x >> 6);
    const int lane = threadIdx.x & 63;
    const float l0 = attnw[(size_t)bt * nSq + lane];
    const float l1 = attnw[(size_t)bt * nSq + lane + 64];
    float m = fmaxf(l0, l1);
    #pragma unroll
    for (int off = 32; off >= 1; off >>= 1)
        m = fmaxf(m, __shfl_xor(m, off));
    const float e0 = __builtin_amdgcn_exp2f((l0 - m) * LOG2E);
    const float e1 = __builtin_amdgcn_exp2f((l1 - m) * LOG2E);
    float sum = e0 + e1;
    #pragma unroll
    for (int off = 32; off >= 1; off >>= 1)
        sum += __shfl_xor(sum, off);
    const float inv = __builtin_amdgcn_rcpf(sum);
    const float w0 = e0 * inv, w1 = e1 * inv;
    attnw[(size_t)bt * nSq + lane]      = w0;
    attnw[(size_t)bt * nSq + lane + 64] = w1;
    attnbf[(size_t)bt * nSq + lane]      = to_bf(w0);
    attnbf[(size_t)bt * nSq + lane + 64] = to_bf(w1);
}

// ---- kCtxMM: ctx[b] = attn_bf[b] @ encT[b]^T (r9/r10-proven) ------------
__global__ __launch_bounds__(256) void kCtxMM(
    const unsigned short* __restrict__ attnbf,  // [B*T,S]
    const unsigned short* __restrict__ encT,    // [B*E,S]
    float* __restrict__ ctx)                    // [B*T,E]
{
    const int b  = blockIdx.z;
    const int tB = blockIdx.y * 32;
    const int eB = blockIdx.x * 64;

    __shared__ unsigned short sA[32][136];
    __shared__ unsigned short sB[64][136];

    const int tid  = threadIdx.x;
    const int lane = tid & 63;
    const int w    = tid >> 6;
    const int wm = (w >> 1) * 16;
    const int wn = (w & 1) * 32;
    const int l15 = lane & 15;
    const int kh  = lane >> 4;

    {
        const int r = tid >> 3, c = (tid & 7) * 16;
        const size_t o = ((size_t)b * nTq + tB + r) * nSq + c;
        *(s16x8*)&sA[r][c]     = *(const s16x8*)&attnbf[o];
        *(s16x8*)&sA[r][c + 8] = *(const s16x8*)&attnbf[o + 8];
    }
    {
        const int r = tid >> 2, c = (tid & 3) * 32;
        const size_t o = ((size_t)b * nEd + eB + r) * nSq + c;
        *(s16x8*)&sB[r][c]      = *(const s16x8*)&encT[o];
        *(s16x8*)&sB[r][c + 8]  = *(const s16x8*)&encT[o + 8];
        *(s16x8*)&sB[r][c + 16] = *(const s16x8*)&encT[o + 16];
        *(s16x8*)&sB[r][c + 24] = *(const s16x8*)&encT[o + 24];
    }
    __syncthreads();

    f32x4 acc[2] = {};
    #pragma unroll
    for (int kk = 0; kk < 4; ++kk) {
        const s16x8 fA = *(const s16x8*)&sA[wm + l15][kk * 32 + kh * 8];
        #pragma unroll
        for (int ni = 0; ni < 2; ++ni) {
            const s16x8 fB = *(const s16x8*)&sB[wn + ni * 16 + l15][kk * 32 + kh * 8];
            acc[ni] = __builtin_amdgcn_mfma_f32_16x16x32_bf16(fA, fB, acc[ni], 0, 0, 0);
        }
    }

    #pragma unroll
    for (int ni = 0; ni < 2; ++ni) {
        const int e = eB + wn + ni * 16 + l15;
        #pragma unroll
        for (int r = 0; r < 4; ++r) {
            const int t = tB + wm + kh * 4 + r;
            ctx[((size_t)b * nTq + t) * nEd + e] = acc[ni][r];
        }
    }
}

extern "C" void kernel_launch(void* const* d_in, const int* in_sizes, int n_in,
                              void* d_out, int out_size, void* d_ws, size_t ws_size,
                              hipStream_t stream) {
    const float* enc = (const float*)d_in[0];   // [16,128,512]
    const float* dec = (const float*)d_in[1];   // [16,128,512]
    const float* W1  = (const float*)d_in[2];   // [512,512]
    const float* W2  = (const float*)d_in[3];   // [512,512]
    const float* bv  = (const float*)d_in[4];   // [512]
    const float* V   = (const float*)d_in[5];   // [512]

    float* ctx   = (float*)d_out;                           // [16,128,512] 4MB
    float* attnw = (float*)d_out + (size_t)nBt * nTq * nEd; // [16,128,128] 1MB

    // WT (2MB) in ctx region — dead before kCtxMM writes ctx.
    unsigned short* WT = (unsigned short*)d_out;

    float* ws0 = (float*)d_ws;                    // exp2((enc@W1)*PS), 4MB
    float* ws1 = ws0 + (size_t)nBt * nSq * nEd;   // exp2((dec@W2+b)*PS), 4MB
    // After kLogits, X1e region is reused:
    unsigned short* encT   = (unsigned short*)d_ws;                        // 2MB
    unsigned short* attnbf = (unsigned short*)((char*)d_ws + 2*1024*1024); // 512KB

    kWprep<<<dim3(nEd / 32, nEd / 32, 2), dim3(256), 0, stream>>>(W1, W2, WT);
    kMgemmB<<<dim3(nEd / 128, (nBt * nSq) / 32, 2), dim3(256), 0, stream>>>(
        enc, dec, WT, bv, ws0, ws1);
    kLogits<<<dim3(4, 16, nBt), dim3(256), 0, stream>>>(ws0, ws1, V, attnw);
    kEncT<<<dim3(nEd / 32, nSq / 32, nBt), dim3(256), 0, stream>>>(enc, encT);
    kSoft<<<dim3((nBt * nTq) / 4), dim3(256), 0, stream>>>(attnw, attnbf);
    kCtxMM<<<dim3(nEd / 64, nTq / 32, nBt), dim3(256), 0, stream>>>(
        attnbf, encT, ctx);
}

// Round 13
// 58.648 us; speedup vs baseline: 1.4452x; 1.0399x over previous
//
#include <hip/hip_runtime.h>
#include <hip/hip_bf16.h>
#include <cstddef>

// Pipeline (5 kernels):
//  kWprep  : W1,W2 -> split-bf16 WT [term][z][n][k] in d_out ctx region (2MB)
//  kMgemmB : split-bf16 3-term MFMA GEMM, 32x128 tile; epilogue stores
//            exp2 of prescaled activation (factored sigmoid)
//  kLogits : register-based factored-sigmoid scores, 4-t sharing (r10-proven;
//            r12 lesson: 8-t = VGPR cliff, ~2x slower)
//  kEncT   : enc -> bf16 transpose encT[b][e][s] in ws (X1e dead by then)
//  kCtxMM  : MFMA batched context GEMM, softmax'd f32 weights converted to
//            bf16 in A-staging (r11-proven; kSoft launch eliminated)
//  kSoftW  : tiny softmax writing f32 weights (needed for attnw output AND
//            kCtxMM input) -- merged INTO kCtxMM is not possible for the
//            attnw output itself, so kSoftW stays but is the only extra.
// NOTE: softmax must still produce attnw (graded output), so we keep kSoftW;
//       kCtxMM consumes its f32 result directly (no bf16 scratch, no kSoft).

constexpr int nBt = 16, nSq = 128, nTq = 128, nEd = 512;

typedef __attribute__((ext_vector_type(4))) float f32x4;
typedef __attribute__((ext_vector_type(8))) short s16x8;

#define PRESCALE 2.8853900817779268f  /* 2*log2(e) */
#define LOG2E 1.4426950408889634f

__device__ __forceinline__ unsigned short to_bf(float f) {
    unsigned u = __builtin_bit_cast(unsigned, f);
    return (unsigned short)((u + 0x7FFFu + ((u >> 16) & 1u)) >> 16);  // RNE
}
__device__ __forceinline__ float from_bf(unsigned short h) {
    unsigned u = ((unsigned)h) << 16;
    return __builtin_bit_cast(float, u);
}

// ---- kWprep: WT[term][z][n][k] = split_bf16(W_z[k][n]) (r8-proven) ------
__global__ __launch_bounds__(256) void kWprep(
    const float* __restrict__ W1, const float* __restrict__ W2,
    unsigned short* __restrict__ WT)
{
    const int z = blockIdx.z;
    const float* W = z ? W2 : W1;
    __shared__ float tl[32][33];
    const int r  = threadIdx.x >> 3;
    const int c4 = (threadIdx.x & 7) * 4;
    const int kB = blockIdx.y * 32;
    const int nB = blockIdx.x * 32;
    const float4 v = *(const float4*)&W[(size_t)(kB + r) * nEd + nB + c4];
    tl[r][c4 + 0] = v.x; tl[r][c4 + 1] = v.y;
    tl[r][c4 + 2] = v.z; tl[r][c4 + 3] = v.w;
    __syncthreads();
    unsigned short hh[4], ll[4];
    #pragma unroll
    for (int i = 0; i < 4; ++i) {
        const float x = tl[c4 + i][r];
        hh[i] = to_bf(x);
        ll[i] = to_bf(x - from_bf(hh[i]));
    }
    const size_t o = ((size_t)z * nEd + nB + r) * nEd + kB + c4;
    *(ushort4*)&WT[o] = *(ushort4*)hh;
    *(ushort4*)&WT[(size_t)2 * nEd * nEd + o] = *(ushort4*)ll;
}

// ---- kMgemmB: C_z = exp2((A_z @ W_z [+bias]) * PRESCALE) (r11/12-proven) -
__global__ __launch_bounds__(256) void kMgemmB(
    const float* __restrict__ A0, const float* __restrict__ A1,
    const unsigned short* __restrict__ WT, const float* __restrict__ bias,
    float* __restrict__ C0, float* __restrict__ C1)
{
    const int z = blockIdx.z;
    const float* __restrict__ A = z ? A1 : A0;
    const unsigned short* __restrict__ Wh = WT + (size_t)z * nEd * nEd;
    const unsigned short* __restrict__ Wl = Wh + (size_t)2 * nEd * nEd;
    float* __restrict__ C = z ? C1 : C0;

    __shared__ unsigned short sAh[32][72];
    __shared__ unsigned short sAl[32][72];
    __shared__ unsigned short sBh[128][72];
    __shared__ unsigned short sBl[128][72];

    const int tid  = threadIdx.x;
    const int lane = tid & 63;
    const int wv   = tid >> 6;
    const int rowB = blockIdx.y * 32;
    const int colB = blockIdx.x * 128;

    const int ar = tid >> 3, ak = (tid & 7) * 8;
    const int br = tid >> 1, bc = (tid & 1) * 32;

    f32x4 acc[2][2] = {};
    const int l15 = lane & 15;
    const int kh  = lane >> 4;

    for (int k0 = 0; k0 < nEd; k0 += 64) {
        const float4 ga0 = *(const float4*)&A[(size_t)(rowB + ar) * nEd + k0 + ak];
        const float4 ga1 = *(const float4*)&A[(size_t)(rowB + ar) * nEd + k0 + ak + 4];
        const size_t wo = (size_t)(colB + br) * nEd + k0 + bc;
        s16x8 gh[4], gl[4];
        #pragma unroll
        for (int j = 0; j < 4; ++j) {
            gh[j] = *(const s16x8*)&Wh[wo + 8 * j];
            gl[j] = *(const s16x8*)&Wl[wo + 8 * j];
        }

        __syncthreads();
        {
            const float a8[8] = {ga0.x, ga0.y, ga0.z, ga0.w,
                                 ga1.x, ga1.y, ga1.z, ga1.w};
            unsigned short h[8], l[8];
            #pragma unroll
            for (int i = 0; i < 8; ++i) {
                h[i] = to_bf(a8[i]);
                l[i] = to_bf(a8[i] - from_bf(h[i]));
            }
            *(ushort4*)&sAh[ar][ak]     = *(ushort4*)&h[0];
            *(ushort4*)&sAh[ar][ak + 4] = *(ushort4*)&h[4];
            *(ushort4*)&sAl[ar][ak]     = *(ushort4*)&l[0];
            *(ushort4*)&sAl[ar][ak + 4] = *(ushort4*)&l[4];
        }
        #pragma unroll
        for (int j = 0; j < 4; ++j) {
            *(s16x8*)&sBh[br][bc + 8 * j] = gh[j];
            *(s16x8*)&sBl[br][bc + 8 * j] = gl[j];
        }
        __syncthreads();

        #pragma unroll
        for (int kk = 0; kk < 2; ++kk) {
            s16x8 fAh[2], fAl[2], fBh[2], fBl[2];
            #pragma unroll
            for (int mi = 0; mi < 2; ++mi) {
                fAh[mi] = *(const s16x8*)&sAh[mi * 16 + l15][kk * 32 + kh * 8];
                fAl[mi] = *(const s16x8*)&sAl[mi * 16 + l15][kk * 32 + kh * 8];
            }
            #pragma unroll
            for (int ni = 0; ni < 2; ++ni) {
                fBh[ni] = *(const s16x8*)&sBh[wv * 32 + ni * 16 + l15][kk * 32 + kh * 8];
                fBl[ni] = *(const s16x8*)&sBl[wv * 32 + ni * 16 + l15][kk * 32 + kh * 8];
            }
            #pragma unroll
            for (int mi = 0; mi < 2; ++mi)
                #pragma unroll
                for (int ni = 0; ni < 2; ++ni) {
                    f32x4 a = acc[mi][ni];
                    a = __builtin_amdgcn_mfma_f32_16x16x32_bf16(fAh[mi], fBh[ni], a, 0, 0, 0);
                    a = __builtin_amdgcn_mfma_f32_16x16x32_bf16(fAl[mi], fBh[ni], a, 0, 0, 0);
                    a = __builtin_amdgcn_mfma_f32_16x16x32_bf16(fAh[mi], fBl[ni], a, 0, 0, 0);
                    acc[mi][ni] = a;
                }
        }
    }

    #pragma unroll
    for (int ni = 0; ni < 2; ++ni) {
        const int col = colB + wv * 32 + ni * 16 + l15;
        const float bval = z ? bias[col] : 0.0f;
        #pragma unroll
        for (int mi = 0; mi < 2; ++mi) {
            #pragma unroll
            for (int r = 0; r < 4; ++r) {
                const int row = rowB + mi * 16 + kh * 4 + r;
                C[(size_t)row * nEd + col] =
                    __builtin_amdgcn_exp2f((acc[mi][ni][r] + bval) * PRESCALE);
            }
        }
    }
}

// ---- kLogits: factored-sigmoid scores, 4-t sharing (r10-proven exact) ---
__global__ __launch_bounds__(256) void kLogits(
    const float* __restrict__ X1e,  // [B*S,E] exp2'd
    const float* __restrict__ X2e,  // [B*T,E] exp2'd (bias folded)
    const float* __restrict__ V,    // [E]
    float* __restrict__ lg)         // [B*T,S]
{
    const int sg = blockIdx.x, tg = blockIdx.y, b = blockIdx.z;
    const int tid  = threadIdx.x;
    const int lane = tid & 63;
    const int w    = tid >> 6;
    const int s0 = sg * 32 + w * 8;
    const int t0 = tg * 4;

    const float4* vp = (const float4*)V;
    const float4  v0 = vp[lane * 2], v1 = vp[lane * 2 + 1];
    const float4 n0 = make_float4(-2.f * v0.x, -2.f * v0.y, -2.f * v0.z, -2.f * v0.w);
    const float4 n1 = make_float4(-2.f * v1.x, -2.f * v1.y, -2.f * v1.z, -2.f * v1.w);
    const float vsum = v0.x + v0.y + v0.z + v0.w + v1.x + v1.y + v1.z + v1.w;

    float4 c0[4], c1[4];
    #pragma unroll
    for (int i = 0; i < 4; ++i) {
        const float4* xp = (const float4*)(X2e + ((size_t)b * nTq + t0 + i) * nEd);
        c0[i] = xp[lane * 2];
        c1[i] = xp[lane * 2 + 1];
    }

    for (int si = 0; si < 8; ++si) {
        const int s = s0 + si;
        const float4* ap = (const float4*)(X1e + ((size_t)b * nSq + s) * nEd);
        const float4 x0 = ap[lane * 2], x1 = ap[lane * 2 + 1];
        float acc[4];
        #pragma unroll
        for (int t = 0; t < 4; ++t) {
            float a = vsum;
            a += n0.x * __builtin_amdgcn_rcpf(x0.x * c0[t].x + 1.0f);
            a += n0.y * __builtin_amdgcn_rcpf(x0.y * c0[t].y + 1.0f);
            a += n0.z * __builtin_amdgcn_rcpf(x0.z * c0[t].z + 1.0f);
            a += n0.w * __builtin_amdgcn_rcpf(x0.w * c0[t].w + 1.0f);
            a += n1.x * __builtin_amdgcn_rcpf(x1.x * c1[t].x + 1.0f);
            a += n1.y * __builtin_amdgcn_rcpf(x1.y * c1[t].y + 1.0f);
            a += n1.z * __builtin_amdgcn_rcpf(x1.z * c1[t].z + 1.0f);
            a += n1.w * __builtin_amdgcn_rcpf(x1.w * c1[t].w + 1.0f);
            acc[t] = a;
        }
        #pragma unroll
        for (int t = 0; t < 4; ++t) {
            float a = acc[t];
            #pragma unroll
            for (int off = 32; off >= 1; off >>= 1)
                a += __shfl_xor(a, off);
            if (lane == 0)
                lg[((size_t)b * nTq + t0 + t) * nSq + s] = a;
        }
    }
}

// ---- kEncT: encT[b][e][s] = bf16(enc[b][s][e]) (r9-proven) --------------
__global__ __launch_bounds__(256) void kEncT(
    const float* __restrict__ enc, unsigned short* __restrict__ encT)
{
    const int b = blockIdx.z;
    __shared__ float tl[32][33];
    const int r  = threadIdx.x >> 3;
    const int c4 = (threadIdx.x & 7) * 4;
    const int sB = blockIdx.y * 32;
    const int eB = blockIdx.x * 32;
    const float4 v = *(const float4*)&enc[((size_t)b * nSq + sB + r) * nEd + eB + c4];
    tl[r][c4 + 0] = v.x; tl[r][c4 + 1] = v.y;
    tl[r][c4 + 2] = v.z; tl[r][c4 + 3] = v.w;
    __syncthreads();
    unsigned short o[4];
    #pragma unroll
    for (int i = 0; i < 4; ++i) o[i] = to_bf(tl[c4 + i][r]);
    *(ushort4*)&encT[((size_t)b * nEd + eB + r) * nSq + sB + c4] = *(ushort4*)o;
}

// ---- kSoftW: softmax per (b,t), f32 weights in-place (r9-proven core) ---
__global__ __launch_bounds__(256) void kSoftW(float* __restrict__ attnw)
{
    const int bt = blockIdx.x * 4 + (threadIdx.x >> 6);
    const int lane = threadIdx.x & 63;
    const float l0 = attnw[(size_t)bt * nSq + lane];
    const float l1 = attnw[(size_t)bt * nSq + lane + 64];
    float m = fmaxf(l0, l1);
    #pragma unroll
    for (int off = 32; off >= 1; off >>= 1)
        m = fmaxf(m, __shfl_xor(m, off));
    const float e0 = __builtin_amdgcn_exp2f((l0 - m) * LOG2E);
    const float e1 = __builtin_amdgcn_exp2f((l1 - m) * LOG2E);
    float sum = e0 + e1;
    #pragma unroll
    for (int off = 32; off >= 1; off >>= 1)
        sum += __shfl_xor(sum, off);
    const float inv = __builtin_amdgcn_rcpf(sum);
    attnw[(size_t)bt * nSq + lane]      = e0 * inv;
    attnw[(size_t)bt * nSq + lane + 64] = e1 * inv;
}

// ---- kCtxMM: ctx[b] = bf16(attnw[b]) @ encT[b]^T (r11-proven staging) ---
__global__ __launch_bounds__(256) void kCtxMM(
    const float* __restrict__ attnw,          // [B*T,S] f32 weights
    const unsigned short* __restrict__ encT,  // [B*E,S]
    float* __restrict__ ctx)                  // [B*T,E]
{
    const int b  = blockIdx.z;
    const int tB = blockIdx.y * 32;
    const int eB = blockIdx.x * 64;

    __shared__ unsigned short sA[32][136];
    __shared__ unsigned short sB[64][136];

    const int tid  = threadIdx.x;
    const int lane = tid & 63;
    const int w    = tid >> 6;
    const int wm = (w >> 1) * 16;
    const int wn = (w & 1) * 32;
    const int l15 = lane & 15;
    const int kh  = lane >> 4;

    {   // stage A: convert 32x128 f32 weights -> bf16 (16/thread)
        const int r = tid >> 3, c = (tid & 7) * 16;
        const float* ap = &attnw[((size_t)b * nTq + tB + r) * nSq + c];
        unsigned short h[16];
        #pragma unroll
        for (int q = 0; q < 4; ++q) {
            const float4 v = *(const float4*)(ap + 4 * q);
            h[4 * q + 0] = to_bf(v.x); h[4 * q + 1] = to_bf(v.y);
            h[4 * q + 2] = to_bf(v.z); h[4 * q + 3] = to_bf(v.w);
        }
        *(s16x8*)&sA[r][c]     = *(s16x8*)&h[0];
        *(s16x8*)&sA[r][c + 8] = *(s16x8*)&h[8];
    }
    {   // stage B: 64x128 ushorts (32/thread)
        const int r = tid >> 2, c = (tid & 3) * 32;
        const size_t o = ((size_t)b * nEd + eB + r) * nSq + c;
        *(s16x8*)&sB[r][c]      = *(const s16x8*)&encT[o];
        *(s16x8*)&sB[r][c + 8]  = *(const s16x8*)&encT[o + 8];
        *(s16x8*)&sB[r][c + 16] = *(const s16x8*)&encT[o + 16];
        *(s16x8*)&sB[r][c + 24] = *(const s16x8*)&encT[o + 24];
    }
    __syncthreads();

    f32x4 acc[2] = {};
    #pragma unroll
    for (int kk = 0; kk < 4; ++kk) {
        const s16x8 fA = *(const s16x8*)&sA[wm + l15][kk * 32 + kh * 8];
        #pragma unroll
        for (int ni = 0; ni < 2; ++ni) {
            const s16x8 fB = *(const s16x8*)&sB[wn + ni * 16 + l15][kk * 32 + kh * 8];
            acc[ni] = __builtin_amdgcn_mfma_f32_16x16x32_bf16(fA, fB, acc[ni], 0, 0, 0);
        }
    }

    #pragma unroll
    for (int ni = 0; ni < 2; ++ni) {
        const int e = eB + wn + ni * 16 + l15;
        #pragma unroll
        for (int r = 0; r < 4; ++r) {
            const int t = tB + wm + kh * 4 + r;
            ctx[((size_t)b * nTq + t) * nEd + e] = acc[ni][r];
        }
    }
}

extern "C" void kernel_launch(void* const* d_in, const int* in_sizes, int n_in,
                              void* d_out, int out_size, void* d_ws, size_t ws_size,
                              hipStream_t stream) {
    const float* enc = (const float*)d_in[0];   // [16,128,512]
    const float* dec = (const float*)d_in[1];   // [16,128,512]
    const float* W1  = (const float*)d_in[2];   // [512,512]
    const float* W2  = (const float*)d_in[3];   // [512,512]
    const float* bv  = (const float*)d_in[4];   // [512]
    const float* V   = (const float*)d_in[5];   // [512]

    float* ctx   = (float*)d_out;                           // [16,128,512] 4MB
    float* attnw = (float*)d_out + (size_t)nBt * nTq * nEd; // [16,128,128] 1MB

    // WT (2MB) in ctx region — dead before kCtxMM writes ctx.
    unsigned short* WT = (unsigned short*)d_out;

    float* ws0 = (float*)d_ws;                    // exp2((enc@W1)*PS), 4MB
    float* ws1 = ws0 + (size_t)nBt * nSq * nEd;   // exp2((dec@W2+b)*PS), 4MB
    // After kLogits, X1e region is reused:
    unsigned short* encT = (unsigned short*)d_ws;           // 2MB

    kWprep<<<dim3(nEd / 32, nEd / 32, 2), dim3(256), 0, stream>>>(W1, W2, WT);
    kMgemmB<<<dim3(nEd / 128, (nBt * nSq) / 32, 2), dim3(256), 0, stream>>>(
        enc, dec, WT, bv, ws0, ws1);
    kLogits<<<dim3(4, 32, nBt), dim3(256), 0, stream>>>(ws0, ws1, V, attnw);
    kEncT<<<dim3(nEd / 32, nSq / 32, nBt), dim3(256), 0, stream>>>(enc, encT);
    kSoftW<<<dim3((nBt * nTq) / 4), dim3(256), 0, stream>>>(attnw);
    kCtxMM<<<dim3(nEd / 64, nTq / 32, nBt), dim3(256), 0, stream>>>(
        attnw, encT, ctx);
}

// Round 14
// 52.330 us; speedup vs baseline: 1.6197x; 1.1207x over previous
//
#include <hip/hip_runtime.h>
#include <hip/hip_bf16.h>
#include <cstddef>

// Pipeline:
//  kPrep   : W split-bf16 transpose (+ encT transpose when ws has room)
//  kMgemmB : split-bf16 3-term MFMA GEMM, 32x128 tile; epilogue stores
//            exp2 of prescaled activation (factored sigmoid)
//  kLogits : factored-sigmoid scores, 4-t sharing, SW-pipelined X1 loads,
//            10-shuffle reduction (r13: 24 shuffles + exposed load latency)
//  kEncT   : standalone fallback when encT must reuse X1e space
//  kSoftW  : softmax per (b,t), f32 weights in-place
//  kCtxMM  : MFMA batched context GEMM, f32->bf16 weights in A-staging

constexpr int nBt = 16, nSq = 128, nTq = 128, nEd = 512;

typedef __attribute__((ext_vector_type(4))) float f32x4;
typedef __attribute__((ext_vector_type(8))) short s16x8;

#define PRESCALE 2.8853900817779268f  /* 2*log2(e) */
#define LOG2E 1.4426950408889634f

__device__ __forceinline__ unsigned short to_bf(float f) {
    unsigned u = __builtin_bit_cast(unsigned, f);
    return (unsigned short)((u + 0x7FFFu + ((u >> 16) & 1u)) >> 16);  // RNE
}
__device__ __forceinline__ float from_bf(unsigned short h) {
    unsigned u = ((unsigned)h) << 16;
    return __builtin_bit_cast(float, u);
}

// ---- kPrep: [0,512) W-split blocks; [512,1536) encT blocks (if early) ---
__global__ __launch_bounds__(256) void kPrep(
    const float* __restrict__ W1, const float* __restrict__ W2,
    unsigned short* __restrict__ WT,
    const float* __restrict__ enc, unsigned short* __restrict__ encT)
{
    __shared__ float tl[32][33];
    const int r  = threadIdx.x >> 3;
    const int c4 = (threadIdx.x & 7) * 4;
    int bid = blockIdx.x;

    if (bid < 512) {   // W split-transpose (r8-proven math)
        const int z = bid >> 8;
        const int yx = bid & 255;
        const int kB = (yx >> 4) * 32;
        const int nB = (yx & 15) * 32;
        const float* W = z ? W2 : W1;
        const float4 v = *(const float4*)&W[(size_t)(kB + r) * nEd + nB + c4];
        tl[r][c4 + 0] = v.x; tl[r][c4 + 1] = v.y;
        tl[r][c4 + 2] = v.z; tl[r][c4 + 3] = v.w;
        __syncthreads();
        unsigned short hh[4], ll[4];
        #pragma unroll
        for (int i = 0; i < 4; ++i) {
            const float x = tl[c4 + i][r];
            hh[i] = to_bf(x);
            ll[i] = to_bf(x - from_bf(hh[i]));
        }
        const size_t o = ((size_t)z * nEd + nB + r) * nEd + kB + c4;
        *(ushort4*)&WT[o] = *(ushort4*)hh;
        *(ushort4*)&WT[(size_t)2 * nEd * nEd + o] = *(ushort4*)ll;
    } else {           // encT transpose (r9-proven math)
        bid -= 512;
        const int b = bid >> 6;
        const int r6 = bid & 63;
        const int eB = (r6 & 15) * 32;
        const int sB = (r6 >> 4) * 32;
        const float4 v = *(const float4*)&enc[((size_t)b * nSq + sB + r) * nEd + eB + c4];
        tl[r][c4 + 0] = v.x; tl[r][c4 + 1] = v.y;
        tl[r][c4 + 2] = v.z; tl[r][c4 + 3] = v.w;
        __syncthreads();
        unsigned short o[4];
        #pragma unroll
        for (int i = 0; i < 4; ++i) o[i] = to_bf(tl[c4 + i][r]);
        *(ushort4*)&encT[((size_t)b * nEd + eB + r) * nSq + sB + c4] = *(ushort4*)o;
    }
}

// ---- kEncT: standalone fallback (r9-proven) -----------------------------
__global__ __launch_bounds__(256) void kEncT(
    const float* __restrict__ enc, unsigned short* __restrict__ encT)
{
    const int b = blockIdx.z;
    __shared__ float tl[32][33];
    const int r  = threadIdx.x >> 3;
    const int c4 = (threadIdx.x & 7) * 4;
    const int sB = blockIdx.y * 32;
    const int eB = blockIdx.x * 32;
    const float4 v = *(const float4*)&enc[((size_t)b * nSq + sB + r) * nEd + eB + c4];
    tl[r][c4 + 0] = v.x; tl[r][c4 + 1] = v.y;
    tl[r][c4 + 2] = v.z; tl[r][c4 + 3] = v.w;
    __syncthreads();
    unsigned short o[4];
    #pragma unroll
    for (int i = 0; i < 4; ++i) o[i] = to_bf(tl[c4 + i][r]);
    *(ushort4*)&encT[((size_t)b * nEd + eB + r) * nSq + sB + c4] = *(ushort4*)o;
}

// ---- kMgemmB: C_z = exp2((A_z @ W_z [+bias]) * PRESCALE) (r11-13 proven)
__global__ __launch_bounds__(256) void kMgemmB(
    const float* __restrict__ A0, const float* __restrict__ A1,
    const unsigned short* __restrict__ WT, const float* __restrict__ bias,
    float* __restrict__ C0, float* __restrict__ C1)
{
    const int z = blockIdx.z;
    const float* __restrict__ A = z ? A1 : A0;
    const unsigned short* __restrict__ Wh = WT + (size_t)z * nEd * nEd;
    const unsigned short* __restrict__ Wl = Wh + (size_t)2 * nEd * nEd;
    float* __restrict__ C = z ? C1 : C0;

    __shared__ unsigned short sAh[32][72];
    __shared__ unsigned short sAl[32][72];
    __shared__ unsigned short sBh[128][72];
    __shared__ unsigned short sBl[128][72];

    const int tid  = threadIdx.x;
    const int lane = tid & 63;
    const int wv   = tid >> 6;
    const int rowB = blockIdx.y * 32;
    const int colB = blockIdx.x * 128;

    const int ar = tid >> 3, ak = (tid & 7) * 8;
    const int br = tid >> 1, bc = (tid & 1) * 32;

    f32x4 acc[2][2] = {};
    const int l15 = lane & 15;
    const int kh  = lane >> 4;

    for (int k0 = 0; k0 < nEd; k0 += 64) {
        const float4 ga0 = *(const float4*)&A[(size_t)(rowB + ar) * nEd + k0 + ak];
        const float4 ga1 = *(const float4*)&A[(size_t)(rowB + ar) * nEd + k0 + ak + 4];
        const size_t wo = (size_t)(colB + br) * nEd + k0 + bc;
        s16x8 gh[4], gl[4];
        #pragma unroll
        for (int j = 0; j < 4; ++j) {
            gh[j] = *(const s16x8*)&Wh[wo + 8 * j];
            gl[j] = *(const s16x8*)&Wl[wo + 8 * j];
        }

        __syncthreads();
        {
            const float a8[8] = {ga0.x, ga0.y, ga0.z, ga0.w,
                                 ga1.x, ga1.y, ga1.z, ga1.w};
            unsigned short h[8], l[8];
            #pragma unroll
            for (int i = 0; i < 8; ++i) {
                h[i] = to_bf(a8[i]);
                l[i] = to_bf(a8[i] - from_bf(h[i]));
            }
            *(ushort4*)&sAh[ar][ak]     = *(ushort4*)&h[0];
            *(ushort4*)&sAh[ar][ak + 4] = *(ushort4*)&h[4];
            *(ushort4*)&sAl[ar][ak]     = *(ushort4*)&l[0];
            *(ushort4*)&sAl[ar][ak + 4] = *(ushort4*)&l[4];
        }
        #pragma unroll
        for (int j = 0; j < 4; ++j) {
            *(s16x8*)&sBh[br][bc + 8 * j] = gh[j];
            *(s16x8*)&sBl[br][bc + 8 * j] = gl[j];
        }
        __syncthreads();

        #pragma unroll
        for (int kk = 0; kk < 2; ++kk) {
            s16x8 fAh[2], fAl[2], fBh[2], fBl[2];
            #pragma unroll
            for (int mi = 0; mi < 2; ++mi) {
                fAh[mi] = *(const s16x8*)&sAh[mi * 16 + l15][kk * 32 + kh * 8];
                fAl[mi] = *(const s16x8*)&sAl[mi * 16 + l15][kk * 32 + kh * 8];
            }
            #pragma unroll
            for (int ni = 0; ni < 2; ++ni) {
                fBh[ni] = *(const s16x8*)&sBh[wv * 32 + ni * 16 + l15][kk * 32 + kh * 8];
                fBl[ni] = *(const s16x8*)&sBl[wv * 32 + ni * 16 + l15][kk * 32 + kh * 8];
            }
            #pragma unroll
            for (int mi = 0; mi < 2; ++mi)
                #pragma unroll
                for (int ni = 0; ni < 2; ++ni) {
                    f32x4 a = acc[mi][ni];
                    a = __builtin_amdgcn_mfma_f32_16x16x32_bf16(fAh[mi], fBh[ni], a, 0, 0, 0);
                    a = __builtin_amdgcn_mfma_f32_16x16x32_bf16(fAl[mi], fBh[ni], a, 0, 0, 0);
                    a = __builtin_amdgcn_mfma_f32_16x16x32_bf16(fAh[mi], fBl[ni], a, 0, 0, 0);
                    acc[mi][ni] = a;
                }
        }
    }

    #pragma unroll
    for (int ni = 0; ni < 2; ++ni) {
        const int col = colB + wv * 32 + ni * 16 + l15;
        const float bval = z ? bias[col] : 0.0f;
        #pragma unroll
        for (int mi = 0; mi < 2; ++mi) {
            #pragma unroll
            for (int r = 0; r < 4; ++r) {
                const int row = rowB + mi * 16 + kh * 4 + r;
                C[(size_t)row * nEd + col] =
                    __builtin_amdgcn_exp2f((acc[mi][ni][r] + bval) * PRESCALE);
            }
        }
    }
}

// ---- kLogits: 4-t factored-sigmoid, SW-pipelined, 10-shuffle reduce -----
__global__ __launch_bounds__(256) void kLogits(
    const float* __restrict__ X1e,  // [B*S,E] exp2'd
    const float* __restrict__ X2e,  // [B*T,E] exp2'd (bias folded)
    const float* __restrict__ V,    // [E]
    float* __restrict__ lg)         // [B*T,S]
{
    const int sg = blockIdx.x, tg = blockIdx.y, b = blockIdx.z;
    const int tid  = threadIdx.x;
    const int lane = tid & 63;
    const int w    = tid >> 6;
    const int s0 = sg * 32 + w * 8;
    const int t0 = tg * 4;

    const float4* vp = (const float4*)V;
    const float4  v0 = vp[lane * 2], v1 = vp[lane * 2 + 1];
    const float4 n0 = make_float4(-2.f * v0.x, -2.f * v0.y, -2.f * v0.z, -2.f * v0.w);
    const float4 n1 = make_float4(-2.f * v1.x, -2.f * v1.y, -2.f * v1.z, -2.f * v1.w);

    float4 c0[4], c1[4];
    #pragma unroll
    for (int i = 0; i < 4; ++i) {
        const float4* xp = (const float4*)(X2e + ((size_t)b * nTq + t0 + i) * nEd);
        c0[i] = xp[lane * 2];
        c1[i] = xp[lane * 2 + 1];
    }

    const float* X1b = X1e + (size_t)b * nSq * nEd;
    // prefetch row si = 0
    float4 x0 = ((const float4*)(X1b + (size_t)s0 * nEd))[lane * 2];
    float4 x1 = ((const float4*)(X1b + (size_t)s0 * nEd))[lane * 2 + 1];

    #pragma unroll
    for (int si = 0; si < 8; ++si) {
        const float4 cx0 = x0, cx1 = x1;
        if (si < 7) {   // software-pipeline: issue next row's loads now
            const float4* np = (const float4*)(X1b + (size_t)(s0 + si + 1) * nEd);
            x0 = np[lane * 2];
            x1 = np[lane * 2 + 1];
        }
        float acc[4];
        #pragma unroll
        for (int t = 0; t < 4; ++t) {
            float a;
            a  = n0.x * __builtin_amdgcn_rcpf(cx0.x * c0[t].x + 1.0f);
            a += n0.y * __builtin_amdgcn_rcpf(cx0.y * c0[t].y + 1.0f);
            a += n0.z * __builtin_amdgcn_rcpf(cx0.z * c0[t].z + 1.0f);
            a += n0.w * __builtin_amdgcn_rcpf(cx0.w * c0[t].w + 1.0f);
            a += n1.x * __builtin_amdgcn_rcpf(cx1.x * c1[t].x + 1.0f);
            a += n1.y * __builtin_amdgcn_rcpf(cx1.y * c1[t].y + 1.0f);
            a += n1.z * __builtin_amdgcn_rcpf(cx1.z * c1[t].z + 1.0f);
            a += n1.w * __builtin_amdgcn_rcpf(cx1.w * c1[t].w + 1.0f);
            acc[t] = a;
        }
        // 10-shuffle reduce: lane&3 == t ends with full sum for t
        float t01a = acc[0] + __shfl_xor(acc[0], 1);
        float t01b = acc[1] + __shfl_xor(acc[1], 1);
        float a01  = (lane & 1) ? t01b : t01a;
        float t23a = acc[2] + __shfl_xor(acc[2], 1);
        float t23b = acc[3] + __shfl_xor(acc[3], 1);
        float a23  = (lane & 1) ? t23b : t23a;
        float q01 = a01 + __shfl_xor(a01, 2);
        float q23 = a23 + __shfl_xor(a23, 2);
        float q = (lane & 2) ? q23 : q01;
        q += __shfl_xor(q, 4);
        q += __shfl_xor(q, 8);
        q += __shfl_xor(q, 16);
        q += __shfl_xor(q, 32);
        if (lane < 4)
            lg[((size_t)b * nTq + t0 + lane) * nSq + s0 + si] = q;
    }
}

// ---- kSoftW: softmax per (b,t), f32 weights in-place (r13-proven) -------
__global__ __launch_bounds__(256) void kSoftW(float* __restrict__ attnw)
{
    const int bt = blockIdx.x * 4 + (threadIdx.x >> 6);
    const int lane = threadIdx.x & 63;
    const float l0 = attnw[(size_t)bt * nSq + lane];
    const float l1 = attnw[(size_t)bt * nSq + lane + 64];
    float m = fmaxf(l0, l1);
    #pragma unroll
    for (int off = 32; off >= 1; off >>= 1)
        m = fmaxf(m, __shfl_xor(m, off));
    const float e0 = __builtin_amdgcn_exp2f((l0 - m) * LOG2E);
    const float e1 = __builtin_amdgcn_exp2f((l1 - m) * LOG2E);
    float sum = e0 + e1;
    #pragma unroll
    for (int off = 32; off >= 1; off >>= 1)
        sum += __shfl_xor(sum, off);
    const float inv = __builtin_amdgcn_rcpf(sum);
    attnw[(size_t)bt * nSq + lane]      = e0 * inv;
    attnw[(size_t)bt * nSq + lane + 64] = e1 * inv;
}

// ---- kCtxMM: ctx[b] = bf16(attnw[b]) @ encT[b]^T (r13-proven) -----------
__global__ __launch_bounds__(256) void kCtxMM(
    const float* __restrict__ attnw,          // [B*T,S] f32 weights
    const unsigned short* __restrict__ encT,  // [B*E,S]
    float* __restrict__ ctx)                  // [B*T,E]
{
    const int b  = blockIdx.z;
    const int tB = blockIdx.y * 32;
    const int eB = blockIdx.x * 64;

    __shared__ unsigned short sA[32][136];
    __shared__ unsigned short sB[64][136];

    const int tid  = threadIdx.x;
    const int lane = tid & 63;
    const int w    = tid >> 6;
    const int wm = (w >> 1) * 16;
    const int wn = (w & 1) * 32;
    const int l15 = lane & 15;
    const int kh  = lane >> 4;

    {   // stage A: convert 32x128 f32 weights -> bf16 (16/thread)
        const int r = tid >> 3, c = (tid & 7) * 16;
        const float* ap = &attnw[((size_t)b * nTq + tB + r) * nSq + c];
        unsigned short h[16];
        #pragma unroll
        for (int q = 0; q < 4; ++q) {
            const float4 v = *(const float4*)(ap + 4 * q);
            h[4 * q + 0] = to_bf(v.x); h[4 * q + 1] = to_bf(v.y);
            h[4 * q + 2] = to_bf(v.z); h[4 * q + 3] = to_bf(v.w);
        }
        *(s16x8*)&sA[r][c]     = *(s16x8*)&h[0];
        *(s16x8*)&sA[r][c + 8] = *(s16x8*)&h[8];
    }
    {   // stage B: 64x128 ushorts (32/thread)
        const int r = tid >> 2, c = (tid & 3) * 32;
        const size_t o = ((size_t)b * nEd + eB + r) * nSq + c;
        *(s16x8*)&sB[r][c]      = *(const s16x8*)&encT[o];
        *(s16x8*)&sB[r][c + 8]  = *(const s16x8*)&encT[o + 8];
        *(s16x8*)&sB[r][c + 16] = *(const s16x8*)&encT[o + 16];
        *(s16x8*)&sB[r][c + 24] = *(const s16x8*)&encT[o + 24];
    }
    __syncthreads();

    f32x4 acc[2] = {};
    #pragma unroll
    for (int kk = 0; kk < 4; ++kk) {
        const s16x8 fA = *(const s16x8*)&sA[wm + l15][kk * 32 + kh * 8];
        #pragma unroll
        for (int ni = 0; ni < 2; ++ni) {
            const s16x8 fB = *(const s16x8*)&sB[wn + ni * 16 + l15][kk * 32 + kh * 8];
            acc[ni] = __builtin_amdgcn_mfma_f32_16x16x32_bf16(fA, fB, acc[ni], 0, 0, 0);
        }
    }

    #pragma unroll
    for (int ni = 0; ni < 2; ++ni) {
        const int e = eB + wn + ni * 16 + l15;
        #pragma unroll
        for (int r = 0; r < 4; ++r) {
            const int t = tB + wm + kh * 4 + r;
            ctx[((size_t)b * nTq + t) * nEd + e] = acc[ni][r];
        }
    }
}

extern "C" void kernel_launch(void* const* d_in, const int* in_sizes, int n_in,
                              void* d_out, int out_size, void* d_ws, size_t ws_size,
                              hipStream_t stream) {
    const float* enc = (const float*)d_in[0];   // [16,128,512]
    const float* dec = (const float*)d_in[1];   // [16,128,512]
    const float* W1  = (const float*)d_in[2];   // [512,512]
    const float* W2  = (const float*)d_in[3];   // [512,512]
    const float* bv  = (const float*)d_in[4];   // [512]
    const float* V   = (const float*)d_in[5];   // [512]

    float* ctx   = (float*)d_out;                           // [16,128,512] 4MB
    float* attnw = (float*)d_out + (size_t)nBt * nTq * nEd; // [16,128,128] 1MB

    // WT (2MB) in ctx region — dead before kCtxMM writes ctx.
    unsigned short* WT = (unsigned short*)d_out;

    float* ws0 = (float*)d_ws;                    // exp2((enc@W1)*PS), 4MB
    float* ws1 = ws0 + (size_t)nBt * nSq * nEd;   // exp2((dec@W2+b)*PS), 4MB

    const size_t eight_mb = (size_t)8 * 1024 * 1024;
    const bool early = ws_size >= eight_mb + (size_t)2 * 1024 * 1024 + 4096;
    // early: encT in dedicated ws space (can transpose up-front, 1 fewer launch)
    // else : encT reuses X1e region (must wait until after kLogits, r13 path)
    unsigned short* encT = early
        ? (unsigned short*)((char*)d_ws + eight_mb)
        : (unsigned short*)d_ws;

    if (early) {
        kPrep<<<dim3(1536), dim3(256), 0, stream>>>(W1, W2, WT, enc, encT);
        kMgemmB<<<dim3(nEd / 128, (nBt * nSq) / 32, 2), dim3(256), 0, stream>>>(
            enc, dec, WT, bv, ws0, ws1);
        kLogits<<<dim3(4, 32, nBt), dim3(256), 0, stream>>>(ws0, ws1, V, attnw);
    } else {
        kPrep<<<dim3(512), dim3(256), 0, stream>>>(W1, W2, WT, enc, encT);
        kMgemmB<<<dim3(nEd / 128, (nBt * nSq) / 32, 2), dim3(256), 0, stream>>>(
            enc, dec, WT, bv, ws0, ws1);
        kLogits<<<dim3(4, 32, nBt), dim3(256), 0, stream>>>(ws0, ws1, V, attnw);
        kEncT<<<dim3(nEd / 32, nSq / 32, nBt), dim3(256), 0, stream>>>(enc, encT);
    }
    kSoftW<<<dim3((nBt * nTq) / 4), dim3(256), 0, stream>>>(attnw);
    kCtxMM<<<dim3(nEd / 64, nTq / 32, nBt), dim3(256), 0, stream>>>(
        attnw, encT, ctx);
}